// Round 5
// baseline (25.589 us; speedup 1.0000x reference)
//
#include <hip/hip_runtime.h>

#define LEN    16384
#define NB     128
#define LOUT   16513         // LEN + 2*128 - 128 + 1
#define SPAN4  2148          // staged float4s per block
#define SPAN   (SPAN4*4)     // 8592 bf16 values (17184 B LDS)

typedef __attribute__((ext_vector_type(8))) short bf16x8;
typedef __attribute__((ext_vector_type(4))) float f32x4;

__device__ __forceinline__ unsigned short f2bf(float f) {
    union { float f; unsigned u; } c; c.f = f;
    unsigned r = c.u + 0x7FFF + ((c.u >> 16) & 1);   // RNE
    return (unsigned short)(r >> 16);
}

// y[b,t] = sum_k filt[b,k] * xp[b, t+k],  xp[i] = x[i-128] zero-padded
// filt[b,t] = A_b[t] + Sb * B[t]
//   A_b[t] = fc_b[t] + H[t] - (xl*G0[t] + x0*G2[t])/L      (x0,xl scalars)
//   B[t]   = (G0[t]+G1[t]+G2[t])/L                          (batch-independent)
//   G_r[t] = sum_c fc_w[t,c]*conv_w[c,r],  H[t] = sum_c fc_w[t,c]*conv_b[c]
__global__ __launch_bounds__(512) void fused_fir(
    const float* __restrict__ x, const float* __restrict__ conv_w,
    const float* __restrict__ conv_b, const float* __restrict__ fc_w,
    const float* __restrict__ fc_b, float* __restrict__ out)
{
    const int b   = blockIdx.y;
    const int h   = blockIdx.x;          // 0: tiles [0,33), 1: tiles [33,65)
    const int tid = threadIdx.x;

    __shared__ unsigned short sxp[SPAN]; // bf16 xp slab for this half
    __shared__ unsigned short fpA[288];  // padded shifted filter A; fpA[j]=A[j-128]
    __shared__ unsigned short fpB[288];  // padded shifted filter B
    __shared__ float parts[8];           // per-wave partial row sums

    const float* xr   = x + (size_t)b * LEN;
    const float4* xr4 = reinterpret_cast<const float4*>(xr);

    // batch scalars (L1 broadcast)
    const float x0 = xr[0];
    const float xl = xr[LEN - 1];

    // ---- issue fc_w fragment loads early (t = tap, q = c-quarter) ----
    const int t = tid >> 2, q = tid & 3;
    const float4* fw4 = reinterpret_cast<const float4*>(fc_w);
    float4 fw[8];
    #pragma unroll
    for (int m = 0; m < 8; ++m) fw[m] = fw4[32 * t + 8 * q + m];

    // ---- full-row read: sum + bf16-stage this half's xp slab ----
    // slab float4 s4 corresponds to xp float4 (s4 + 2112*h - 32)
    float s = 0.f;
    const int sbase = 32 - 2112 * h;
    #pragma unroll
    for (int p = 0; p < 8; ++p) {
        const int g4 = tid + 512 * p;
        float4 v = xr4[g4];
        s += (v.x + v.y) + (v.z + v.w);
        const int s4 = g4 + sbase;
        if (s4 >= 0 && s4 < SPAN4) {
            ushort4 hv;
            hv.x = f2bf(v.x); hv.y = f2bf(v.y); hv.z = f2bf(v.z); hv.w = f2bf(v.w);
            *reinterpret_cast<ushort4*>(&sxp[4 * s4]) = hv;
        }
    }
    // zero-fill pads (xp out-of-range regions)
    {
        const ushort4 z = {0, 0, 0, 0};
        if (h == 0) { if (tid < 32)  *reinterpret_cast<ushort4*>(&sxp[4 * tid]) = z; }
        else        { if (tid < 132) *reinterpret_cast<ushort4*>(&sxp[4 * (2016 + tid)]) = z; }
    }

    // ---- wave-level partial row sum (no barrier yet) ----
    #pragma unroll
    for (int off = 32; off > 0; off >>= 1) s += __shfl_down(s, off, 64);
    if ((tid & 63) == 0) parts[tid >> 6] = s;

    // ---- G0,G1,G2,H partials over c in [32q, 32q+32); conv data via L1 ----
    float g0 = 0.f, g1 = 0.f, g2 = 0.f, hh = 0.f;
    #pragma unroll
    for (int m = 0; m < 8; ++m) {
        const float fv[4] = {fw[m].x, fw[m].y, fw[m].z, fw[m].w};
        #pragma unroll
        for (int jj = 0; jj < 4; ++jj) {
            const int c = 32 * q + 4 * m + jj;
            const float f = fv[jj];
            g0 = fmaf(f, conv_w[3 * c + 0], g0);
            g1 = fmaf(f, conv_w[3 * c + 1], g1);
            g2 = fmaf(f, conv_w[3 * c + 2], g2);
            hh = fmaf(f, conv_b[c], hh);
        }
    }
    g0 += __shfl_xor(g0, 1); g0 += __shfl_xor(g0, 2);
    g1 += __shfl_xor(g1, 1); g1 += __shfl_xor(g1, 2);
    g2 += __shfl_xor(g2, 1); g2 += __shfl_xor(g2, 2);
    hh += __shfl_xor(hh, 1); hh += __shfl_xor(hh, 2);

    if (q == 0) {
        const float invL = 1.0f / (float)LEN;
        const float A = fc_b[t] + hh - invL * fmaf(xl, g0, x0 * g2);
        const float B = invL * ((g0 + g1) + g2);
        fpA[128 + t] = f2bf(A);
        fpB[128 + t] = f2bf(B);
    }
    if (q == 1) { fpA[t] = 0; fpB[t] = 0; }                     // [0,128)
    if (q == 2 && t < 32) { fpA[256 + t] = 0; fpB[256 + t] = 0; } // [256,288)

    __syncthreads();   // the single barrier: sxp, fpA/fpB, parts all visible

    // ---- Sb (cheap broadcast reads) ----
    float Sb = 0.f;
    #pragma unroll
    for (int i = 0; i < 8; ++i) Sb += parts[i];

    // ---- build A/B fragments (shifted filters) ----
    const int l = tid & 63, w = tid >> 6;  // 8 waves
    const int n = l & 15;                  // C-col
    const int g = l >> 4;                  // k-group
    bf16x8 afA[5], afB[5];
    #pragma unroll
    for (int kb = 0; kb < 5; ++kb)
        #pragma unroll
        for (int hf = 0; hf < 2; ++hf)
            #pragma unroll
            for (int j = 0; j < 4; ++j) {
                const int idx = 128 + 32 * kb + 16 * hf + 4 * g + j - n;
                afA[kb][hf * 4 + j] = (short)fpA[idx];
                afB[kb][hf * 4 + j] = (short)fpB[idx];
            }

    // ---- MFMA FIR: wave w handles tiles T = 33h + w + 8*it ----
    float* orow = out + (size_t)b * LOUT;
    #pragma unroll
    for (int it = 0; it < 5; ++it) {
        const int T = 33 * h + w + 8 * it;
        if (T >= 33 + 32 * h) break;               // wave-uniform
        const int sT = T - 33 * h;
        const unsigned short* bp = &sxp[sT * 256 + 16 * n + 4 * g];
        f32x4 accA = {0.f, 0.f, 0.f, 0.f};
        f32x4 accB = {0.f, 0.f, 0.f, 0.f};
        #pragma unroll
        for (int kb = 0; kb < 5; ++kb) {
            ushort4 lo = *reinterpret_cast<const ushort4*>(bp + 32 * kb);
            ushort4 hi = *reinterpret_cast<const ushort4*>(bp + 32 * kb + 16);
            bf16x8 bfrag;
            bfrag[0] = (short)lo.x; bfrag[1] = (short)lo.y;
            bfrag[2] = (short)lo.z; bfrag[3] = (short)lo.w;
            bfrag[4] = (short)hi.x; bfrag[5] = (short)hi.y;
            bfrag[6] = (short)hi.z; bfrag[7] = (short)hi.w;
            accA = __builtin_amdgcn_mfma_f32_16x16x32_bf16(afA[kb], bfrag, accA, 0, 0, 0);
            accB = __builtin_amdgcn_mfma_f32_16x16x32_bf16(afB[kb], bfrag, accB, 0, 0, 0);
        }
        const int t0 = 256 * T + 16 * n + 4 * g;
        f32x4 y;
        #pragma unroll
        for (int j = 0; j < 4; ++j) y[j] = fmaf(Sb, accB[j], accA[j]);
        if (T < 64) {
            *reinterpret_cast<f32x4*>(&orow[t0]) = y;
        } else {
            #pragma unroll
            for (int j = 0; j < 4; ++j)
                if (t0 + j < LOUT) orow[t0 + j] = y[j];
        }
    }
}

extern "C" void kernel_launch(void* const* d_in, const int* in_sizes, int n_in,
                              void* d_out, int out_size, void* d_ws, size_t ws_size,
                              hipStream_t stream)
{
    const float* x      = (const float*)d_in[0];
    const float* conv_w = (const float*)d_in[1];
    const float* conv_b = (const float*)d_in[2];
    const float* fc_w   = (const float*)d_in[3];
    const float* fc_b   = (const float*)d_in[4];
    float* out = (float*)d_out;

    fused_fir<<<dim3(2, NB), 512, 0, stream>>>(x, conv_w, conv_b, fc_w, fc_b, out);
}

// Round 6
// 18.359 us; speedup vs baseline: 1.3938x; 1.3938x over previous
//
#include <hip/hip_runtime.h>
#include <hip/hip_bf16.h>

#define LEN   16384
#define NB    128
#define LOUT  16513   // LEN + 2*128 - 128 + 1

typedef __attribute__((ext_vector_type(8))) short bf16x8;
typedef __attribute__((ext_vector_type(4))) float f32x4;

__device__ __forceinline__ unsigned short f2bf(float f) {
    union { float f; unsigned u; } c; c.f = f;
    unsigned r = c.u + 0x7FFF + ((c.u >> 16) & 1);   // RNE
    return (unsigned short)(r >> 16);
}
__device__ __forceinline__ unsigned packbf2(float lo, float hi) {
    __hip_bfloat162 p = __float22bfloat162_rn(make_float2(lo, hi));
    union { __hip_bfloat162 h; unsigned u; } c; c.h = p;
    return c.u;
}

template<bool CHECK>
__device__ __forceinline__ float4 ldx4(const float4* __restrict__ xr4, int i) {
    if (CHECK) {
        float4 v = make_float4(0.f, 0.f, 0.f, 0.f);
        if ((unsigned)i < 4096u) v = xr4[i];
        return v;
    }
    return xr4[i];
}

template<bool CHECK>
__device__ __forceinline__ void do_tile(const float4* __restrict__ xr4,
                                        const bf16x8* afA, const bf16x8* afB,
                                        int g4base, f32x4& aA, f32x4& aB) {
    #pragma unroll
    for (int kb = 0; kb < 5; ++kb) {
        float4 vlo = ldx4<CHECK>(xr4, g4base + 8 * kb);
        float4 vhi = ldx4<CHECK>(xr4, g4base + 8 * kb + 4);
        union { bf16x8 v8; unsigned u[4]; } bu;
        bu.u[0] = packbf2(vlo.x, vlo.y);
        bu.u[1] = packbf2(vlo.z, vlo.w);
        bu.u[2] = packbf2(vhi.x, vhi.y);
        bu.u[3] = packbf2(vhi.z, vhi.w);
        aA = __builtin_amdgcn_mfma_f32_16x16x32_bf16(afA[kb], bu.v8, aA, 0, 0, 0);
        aB = __builtin_amdgcn_mfma_f32_16x16x32_bf16(afB[kb], bu.v8, aB, 0, 0, 0);
    }
}

// y[b,t] = sum_k filt[b,k]*xp[b,t+k], xp[i]=x[i-128] zero-padded
// filt = A_b + Sb*B;  A_b = fc_b + H - (xl*G0 + x0*G2)/L;  B = (G0+G1+G2)/L
__global__ __launch_bounds__(512) void fused_fir(
    const float* __restrict__ x, const float* __restrict__ conv_w,
    const float* __restrict__ conv_b, const float* __restrict__ fc_w,
    const float* __restrict__ fc_b, float* __restrict__ out)
{
    const int id  = blockIdx.x;
    const int b   = id & (NB - 1);
    const int h   = id >> 7;            // output half; pair (b,h=0/1) shares an XCD
    const int tid = threadIdx.x;

    __shared__ float    scwb[512];      // conv_w[384] ++ conv_b[128]
    __shared__ unsigned fpAB[288];      // packed {A(lo16),B(hi16)} bf16, padded shifted filter
    __shared__ float    parts[8];

    const float*  xr  = x + (size_t)b * LEN;
    const float4* xr4 = reinterpret_cast<const float4*>(xr);
    const float4* fw4 = reinterpret_cast<const float4*>(fc_w);

    // ---- issue loads, oldest-first (vmcnt is in-order per wave) ----
    const float x0 = xr[0];
    const float xl = xr[LEN - 1];
    const float* csrc = (tid < 384) ? (conv_w + tid) : (conv_b + tid - 384);
    const float cstage = *csrc;
    const int t = tid >> 2, q = tid & 3;
    const float fcb = fc_b[t];
    float4 fw[8];
    #pragma unroll
    for (int m = 0; m < 8; ++m) fw[m] = fw4[32 * t + 8 * q + m];
    float4 rv[8];                        // full row slice; summed only at the very end
    #pragma unroll
    for (int p = 0; p < 8; ++p) rv[p] = xr4[tid + 512 * p];

    // ---- stage conv into LDS; barrier #0 (lgkm only — row loads stay in flight) ----
    scwb[tid] = cstage;
    asm volatile("s_waitcnt lgkmcnt(0)" ::: "memory");
    __builtin_amdgcn_s_barrier();
    asm volatile("" ::: "memory");

    // ---- G matvec partials over c in [32q,32q+32) (LDS + regs only) ----
    float g0 = 0.f, g1 = 0.f, g2 = 0.f, hh = 0.f;
    const float4* scw4 = reinterpret_cast<const float4*>(scwb);
    #pragma unroll
    for (int m = 0; m < 8; ++m) {
        const float4 cwA = scw4[24 * q + 3 * m + 0];
        const float4 cwB = scw4[24 * q + 3 * m + 1];
        const float4 cwC = scw4[24 * q + 3 * m + 2];
        const float4 cb  = scw4[96 + 8 * q + m];
        const float f0 = fw[m].x, f1 = fw[m].y, f2 = fw[m].z, f3 = fw[m].w;
        g0 = fmaf(f0, cwA.x, fmaf(f1, cwA.w, fmaf(f2, cwB.z, fmaf(f3, cwC.y, g0))));
        g1 = fmaf(f0, cwA.y, fmaf(f1, cwB.x, fmaf(f2, cwB.w, fmaf(f3, cwC.z, g1))));
        g2 = fmaf(f0, cwA.z, fmaf(f1, cwB.y, fmaf(f2, cwC.x, fmaf(f3, cwC.w, g2))));
        hh = fmaf(f0, cb.x,  fmaf(f1, cb.y,  fmaf(f2, cb.z,  fmaf(f3, cb.w,  hh))));
    }
    g0 += __shfl_xor(g0, 1); g0 += __shfl_xor(g0, 2);
    g1 += __shfl_xor(g1, 1); g1 += __shfl_xor(g1, 2);
    g2 += __shfl_xor(g2, 1); g2 += __shfl_xor(g2, 2);
    hh += __shfl_xor(hh, 1); hh += __shfl_xor(hh, 2);

    if (q == 0) {
        const float invL = 1.0f / (float)LEN;
        const float A = fcb + hh - invL * fmaf(xl, g0, x0 * g2);
        const float B = invL * ((g0 + g1) + g2);
        fpAB[128 + t] = (unsigned)f2bf(A) | ((unsigned)f2bf(B) << 16);
    }
    if (q == 1) fpAB[t] = 0u;                   // [0,128)
    if (q == 2 && t < 32) fpAB[256 + t] = 0u;   // [256,288)

    // ---- barrier #1: filters visible; row loads STILL in flight ----
    asm volatile("s_waitcnt lgkmcnt(0)" ::: "memory");
    __builtin_amdgcn_s_barrier();
    asm volatile("" ::: "memory");

    // ---- build A/B fragments (Toeplitz shift) ----
    const int l = tid & 63, w = tid >> 6;
    const int n = l & 15, g = l >> 4;
    bf16x8 afA[5], afB[5];
    #pragma unroll
    for (int kb = 0; kb < 5; ++kb)
        #pragma unroll
        for (int hf = 0; hf < 2; ++hf)
            #pragma unroll
            for (int j = 0; j < 4; ++j) {
                const unsigned v = fpAB[128 + 32 * kb + 16 * hf + 4 * g + j - n];
                afA[kb][hf * 4 + j] = (short)(v & 0xFFFFu);
                afB[kb][hf * 4 + j] = (short)(v >> 16);
            }

    // ---- MFMA FIR, x read direct from global (L1/L2-hot) ----
    const int Tlim = h ? 65 : 33;
    f32x4 accA[5], accB[5];
    #pragma unroll
    for (int it = 0; it < 5; ++it) {
        const int T = 33 * h + w + 8 * it;
        if (T < Tlim) {
            const int g4base = (256 * T + 16 * n + 4 * g - 128) >> 2;
            f32x4 aA = {0.f, 0.f, 0.f, 0.f}, aB = {0.f, 0.f, 0.f, 0.f};
            if (T == 0 || T >= 63) do_tile<true >(xr4, afA, afB, g4base, aA, aB);
            else                   do_tile<false>(xr4, afA, afB, g4base, aA, aB);
            accA[it] = aA; accB[it] = aB;
        }
    }

    // ---- row sum (first vmcnt-forced wait on rv), then Sb via barrier #2 ----
    float s = 0.f;
    #pragma unroll
    for (int p = 0; p < 8; ++p) s += (rv[p].x + rv[p].y) + (rv[p].z + rv[p].w);
    #pragma unroll
    for (int off = 32; off > 0; off >>= 1) s += __shfl_down(s, off, 64);
    if (l == 0) parts[w] = s;
    asm volatile("s_waitcnt lgkmcnt(0)" ::: "memory");
    __builtin_amdgcn_s_barrier();
    asm volatile("" ::: "memory");
    float Sb = 0.f;
    #pragma unroll
    for (int i = 0; i < 8; ++i) Sb += parts[i];

    // ---- combine y = accA + Sb*accB and store ----
    float* orow = out + (size_t)b * LOUT;
    #pragma unroll
    for (int it = 0; it < 5; ++it) {
        const int T = 33 * h + w + 8 * it;
        if (T < Tlim) {
            f32x4 y;
            #pragma unroll
            for (int j = 0; j < 4; ++j) y[j] = fmaf(Sb, accB[it][j], accA[it][j]);
            const int t0 = 256 * T + 16 * n + 4 * g;
            if (T < 64) {
                *reinterpret_cast<f32x4*>(&orow[t0]) = y;
            } else {
                #pragma unroll
                for (int j = 0; j < 4; ++j)
                    if (t0 + j < LOUT) orow[t0 + j] = y[j];
            }
        }
    }
}

extern "C" void kernel_launch(void* const* d_in, const int* in_sizes, int n_in,
                              void* d_out, int out_size, void* d_ws, size_t ws_size,
                              hipStream_t stream)
{
    const float* x      = (const float*)d_in[0];
    const float* conv_w = (const float*)d_in[1];
    const float* conv_b = (const float*)d_in[2];
    const float* fc_w   = (const float*)d_in[3];
    const float* fc_b   = (const float*)d_in[4];
    float* out = (float*)d_out;

    fused_fir<<<dim3(2 * NB), 512, 0, stream>>>(x, conv_w, conv_b, fc_w, fc_b, out);
}